// Round 5
// baseline (273.142 us; speedup 1.0000x reference)
//
#include <hip/hip_runtime.h>

#define D_MODEL 1024
#define SEQ 2048
#define BATCH 2
#define NH 16
#define DH 64
#define WIN 128
#define DFF 3072

typedef __bf16 bf16x8 __attribute__((ext_vector_type(8)));
typedef float f32x4 __attribute__((ext_vector_type(4)));
typedef unsigned short u16;
typedef unsigned int u32;

__device__ __forceinline__ float b2f(u16 u) {
    unsigned int x = ((unsigned int)u) << 16;
    return __uint_as_float(x);
}
__device__ __forceinline__ u16 f2b(float f) {
    unsigned int x = __float_as_uint(f);
    x += 0x7fffu + ((x >> 16) & 1u);
    return (u16)(x >> 16);
}
__device__ __forceinline__ u32 pk2(float a, float b) {
    return (u32)f2b(a) | ((u32)f2b(b) << 16);
}

// s_waitcnt imm: vmcnt[3:0]|[15:14], exp[6:4], lgkm[11:8]. vmcnt(0), no
// exp/lgkm wait: 0x0F70.
#define WAIT_VMCNT0() __builtin_amdgcn_s_waitcnt(0x0F70)

// ---------------------------------------------------------------- prep
// Fused: 4 weight transposes (f32 -> bf16, [K][N] -> [N][K]) + LN1.
// All parts independent, disjoint outputs; block-uniform branch on bid.
__global__ __launch_bounds__(256) void prep_k(
        const float* __restrict__ x, const float* __restrict__ g1,
        const float* __restrict__ bt1, u16* __restrict__ hbf,
        const float* __restrict__ wqkv, u16* __restrict__ wqkvT,
        const float* __restrict__ wout, u16* __restrict__ woutT,
        const float* __restrict__ wff1, u16* __restrict__ wff1T,
        const float* __restrict__ wff2, u16* __restrict__ wff2T) {
    __shared__ u16 tile[32][33];
    __shared__ float s1[4], s2[4];
    int bid = blockIdx.x;
    if (bid < 10240) {
        const float* in; u16* out; int R, C, loc, gx;
        if (bid < 3072)      { in = wqkv; out = wqkvT; R = 1024; C = 3072; loc = bid;        gx = 96; }
        else if (bid < 4096) { in = wout; out = woutT; R = 1024; C = 1024; loc = bid - 3072; gx = 32; }
        else if (bid < 7168) { in = wff1; out = wff1T; R = 1024; C = 3072; loc = bid - 4096; gx = 96; }
        else                 { in = wff2; out = wff2T; R = 3072; C = 1024; loc = bid - 7168; gx = 32; }
        int bx = loc % gx, by = loc / gx;
        int tx = threadIdx.x & 31, ty = threadIdx.x >> 5;
        int r0 = by * 32, c0 = bx * 32;
#pragma unroll
        for (int i = 0; i < 4; ++i)
            tile[ty + i * 8][tx] = f2b(in[(size_t)(r0 + ty + i * 8) * C + c0 + tx]);
        __syncthreads();
#pragma unroll
        for (int i = 0; i < 4; ++i)
            out[(size_t)(c0 + ty + i * 8) * R + r0 + tx] = tile[tx][ty + i * 8];
    } else {
        int row = bid - 10240;
        const float* xr = x + (size_t)row * D_MODEL;
        float v[4];
        float sum = 0.f, sq = 0.f;
#pragma unroll
        for (int i = 0; i < 4; ++i) {
            v[i] = xr[threadIdx.x + i * 256];
            sum += v[i];
            sq += v[i] * v[i];
        }
#pragma unroll
        for (int off = 32; off > 0; off >>= 1) {
            sum += __shfl_xor(sum, off, 64);
            sq  += __shfl_xor(sq, off, 64);
        }
        int w = threadIdx.x >> 6;
        if ((threadIdx.x & 63) == 0) { s1[w] = sum; s2[w] = sq; }
        __syncthreads();
        sum = s1[0] + s1[1] + s1[2] + s1[3];
        sq  = s2[0] + s2[1] + s2[2] + s2[3];
        float mu = sum * (1.f / D_MODEL);
        float var = sq * (1.f / D_MODEL) - mu * mu;
        float rstd = rsqrtf(var + 1e-5f);
        u16* outr = hbf + (size_t)row * D_MODEL;
#pragma unroll
        for (int i = 0; i < 4; ++i) {
            int c = threadIdx.x + i * 256;
            outr[c] = f2b((v[i] - mu) * rstd * g1[c] + bt1[c]);
        }
    }
}

// ---------------------------------------------------------------- layernorm
__global__ __launch_bounds__(256) void ln_k(
        const float* __restrict__ x, const float* __restrict__ g,
        const float* __restrict__ bta, u16* __restrict__ out) {
    int row = blockIdx.x;
    const float* xr = x + (size_t)row * D_MODEL;
    float v[4];
    float sum = 0.f, sq = 0.f;
#pragma unroll
    for (int i = 0; i < 4; ++i) {
        v[i] = xr[threadIdx.x + i * 256];
        sum += v[i];
        sq += v[i] * v[i];
    }
#pragma unroll
    for (int off = 32; off > 0; off >>= 1) {
        sum += __shfl_xor(sum, off, 64);
        sq  += __shfl_xor(sq, off, 64);
    }
    __shared__ float s1[4], s2[4];
    int w = threadIdx.x >> 6;
    if ((threadIdx.x & 63) == 0) { s1[w] = sum; s2[w] = sq; }
    __syncthreads();
    sum = s1[0] + s1[1] + s1[2] + s1[3];
    sq  = s2[0] + s2[1] + s2[2] + s2[3];
    float mu = sum * (1.f / D_MODEL);
    float var = sq * (1.f / D_MODEL) - mu * mu;
    float rstd = rsqrtf(var + 1e-5f);
    u16* outr = out + (size_t)row * D_MODEL;
#pragma unroll
    for (int i = 0; i < 4; ++i) {
        int c = threadIdx.x + i * 256;
        outr[c] = f2b((v[i] - mu) * rstd * g[c] + bta[c]);
    }
}

// ---------------------------------------------------------------- GEMM 128x64
// For QKV/FF1 (N=3072). 48 KiB LDS -> 3 blocks/CU (12 waves)
// so vmcnt stalls interleave across blocks; grid = 32x48 = 1536 = exactly
// 2 full co-residency rounds (no half-occupancy tail). Same proven sync
// structure as gemm_k: 1 vmcnt(0)+raw-barrier per K-step, dbuf, chunk
// staging with XOR bank swizzle (conflicts=0). Per-wave 64x32, acc[4][2].
template <int GELU, int VSPLIT>
__global__ __launch_bounds__(256, 3) void gemm3_k(
        const u16* __restrict__ A, const u16* __restrict__ Bt,
        const float* __restrict__ bias, u16* __restrict__ Cb,
        u16* __restrict__ vt, int M, int N, int K, int ldc) {
    __shared__ u16 As[2 * 128 * 64];           // 32 KiB
    __shared__ u16 Bs[2 * 64 * 64];            // 16 KiB
    int tid = threadIdx.x;
    int w = tid >> 6, lane = tid & 63;
    int qd = lane >> 4, l15 = lane & 15;

    // grid = (M/128)*(N/64) = 32*48 = 1536. XCD-stripe: 4 m-tiles per XCD
    // (512-row, 1 MiB A stripe stays L2-local per XCD).
    int lin = blockIdx.x;
    int xcd = lin & 7, idx = lin >> 3;         // idx 0..191
    int m0 = (xcd * 4 + (idx & 3)) * 128;
    int n0 = (idx >> 2) * 64;

    // Staging: 24 chunks of 1 KiB (8 rows x 64 cols); wave owns 6.
    // chunks 0-15 = A (128 rows), 16-23 = B (64 rows).
    const u16* gsrc[6];
    u16* ldst[6];
    int nboff[6];                              // elem offset to buffer 1
#pragma unroll
    for (int i = 0; i < 6; ++i) {
        int c = w * 6 + i;                     // 0..23
        int isA = c < 16;
        int cb = isA ? c : c - 16;
        int row = cb * 8 + (lane >> 3);
        int cg = (lane & 7) ^ (row & 7);       // XOR swizzle, global side
        gsrc[i] = (isA ? A + (size_t)(m0 + row) * K
                       : Bt + (size_t)(n0 + row) * K) + cg * 8;
        ldst[i] = (isA ? As : Bs) + cb * 512;
        nboff[i] = isA ? 8192 : 4096;
    }

    int wm = w & 1, wn = w >> 1;               // 2x2 waves, 64x32 each
    f32x4 acc[4][2];
#pragma unroll
    for (int mt = 0; mt < 4; ++mt)
#pragma unroll
        for (int nt = 0; nt < 2; ++nt)
            acc[mt][nt] = (f32x4){0.f, 0.f, 0.f, 0.f};

    int aoff[4][2], boff[2][2];
#pragma unroll
    for (int t = 0; t < 4; ++t) {
        int ar = wm * 64 + t * 16 + l15;
#pragma unroll
        for (int h = 0; h < 2; ++h)
            aoff[t][h] = ar * 64 + (((h * 4 + qd) ^ (ar & 7)) * 8);
    }
#pragma unroll
    for (int t = 0; t < 2; ++t) {
        int br = wn * 32 + t * 16 + l15;
#pragma unroll
        for (int h = 0; h < 2; ++h)
            boff[t][h] = br * 64 + (((h * 4 + qd) ^ (br & 7)) * 8);
    }

    // prologue: stage step 0 into buffer 0
#pragma unroll
    for (int i = 0; i < 6; ++i)
        __builtin_amdgcn_global_load_lds(
            (__attribute__((address_space(1))) void*)(gsrc[i]),
            (__attribute__((address_space(3))) void*)(ldst[i]), 16, 0, 0);

    int nsteps = K >> 6;                       // 16, even

#define TSTEP3(S, RB)                                                       \
    {                                                                       \
        WAIT_VMCNT0();                                                      \
        __builtin_amdgcn_s_barrier();                                       \
        if ((S) + 1 < nsteps) {                                             \
            int k0 = ((S) + 1) << 6;                                        \
            _Pragma("unroll")                                               \
            for (int i = 0; i < 6; ++i)                                     \
                __builtin_amdgcn_global_load_lds(                           \
                    (__attribute__((address_space(1))) void*)(gsrc[i] + k0),\
                    (__attribute__((address_space(3))) void*)(ldst[i] +     \
                        (1 - (RB)) * nboff[i]),                             \
                    16, 0, 0);                                              \
        }                                                                   \
        bf16x8 av[4][2], bv[2][2];                                          \
        _Pragma("unroll")                                                   \
        for (int t = 0; t < 4; ++t)                                         \
            _Pragma("unroll")                                               \
            for (int h = 0; h < 2; ++h)                                     \
                av[t][h] = *(const bf16x8*)&As[aoff[t][h] + (RB) * 8192];   \
        _Pragma("unroll")                                                   \
        for (int t = 0; t < 2; ++t)                                         \
            _Pragma("unroll")                                               \
            for (int h = 0; h < 2; ++h)                                     \
                bv[t][h] = *(const bf16x8*)&Bs[boff[t][h] + (RB) * 4096];   \
        _Pragma("unroll")                                                   \
        for (int mt = 0; mt < 4; ++mt)                                      \
            _Pragma("unroll")                                               \
            for (int nt = 0; nt < 2; ++nt) {                                \
                acc[mt][nt] = __builtin_amdgcn_mfma_f32_16x16x32_bf16(      \
                    av[mt][0], bv[nt][0], acc[mt][nt], 0, 0, 0);            \
                acc[mt][nt] = __builtin_amdgcn_mfma_f32_16x16x32_bf16(      \
                    av[mt][1], bv[nt][1], acc[mt][nt], 0, 0, 0);            \
            }                                                               \
    }

    for (int s = 0; s < nsteps; s += 2) {
        TSTEP3(s, 0);
        TSTEP3(s + 1, 1);
    }

#pragma unroll
    for (int mt = 0; mt < 4; ++mt) {
        int row0 = m0 + wm * 64 + mt * 16 + qd * 4;
#pragma unroll
        for (int nt = 0; nt < 2; ++nt) {
            int col = n0 + wn * 32 + nt * 16 + l15;
            float v[4];
#pragma unroll
            for (int reg = 0; reg < 4; ++reg) {
                v[reg] = acc[mt][nt][reg] + bias[col];
                if (GELU) v[reg] = 0.5f * v[reg] * (1.f + erff(v[reg] * 0.70710678118654752f));
            }
            if (VSPLIT && col >= 2 * D_MODEL) {
                int d = col - 2 * D_MODEL;
                int bh = (row0 >> 11) * NH + (d >> 6);
                ushort4 pkv = {f2b(v[0]), f2b(v[1]), f2b(v[2]), f2b(v[3])};
                *(ushort4*)&vt[((size_t)(bh * DH + (d & 63))) * SEQ + (row0 & (SEQ - 1))] = pkv;
            } else {
#pragma unroll
                for (int reg = 0; reg < 4; ++reg)
                    Cb[(size_t)(row0 + reg) * ldc + col] = f2b(v[reg]);
            }
        }
    }
}

// ---------------------------------------------------------------- GEMM 64x128
// For the N=1024 GEMMs (attn-out, FF2). Grid = 512 blocks, 48 KiB LDS ->
// 3 blocks/CU. Always: bias + resid + f32 out. Per-wave 32x64, acc[2][4].
__global__ __launch_bounds__(256, 3) void gemm_tall_k(
        const u16* __restrict__ A, const u16* __restrict__ Bt,
        const float* __restrict__ bias, const float* __restrict__ resid,
        float* __restrict__ C, int M, int N, int K, int ldc) {
    __shared__ u16 As[2 * 64 * 64];            // 16 KiB
    __shared__ u16 Bs[2 * 128 * 64];           // 32 KiB
    int tid = threadIdx.x;
    int w = tid >> 6, lane = tid & 63;
    int qd = lane >> 4, l15 = lane & 15;

    // grid = (M/64)*(N/128) = 64*8 = 512. XCD-stripe: 8 m-tiles per XCD.
    int lin = blockIdx.x;
    int xcd = lin & 7, idx = lin >> 3;         // idx 0..63
    int m0 = (xcd * 8 + (idx & 7)) * 64;
    int n0 = (idx >> 3) * 128;

    // Staging: 24 chunks of 1 KiB (8 rows x 64 cols); wave owns 6.
    // chunks 0-7 = A (64 rows), 8-23 = B (128 rows).
    const u16* gsrc[6];
    u16* ldst[6];
    int nboff[6];                              // elem offset to buffer 1
#pragma unroll
    for (int i = 0; i < 6; ++i) {
        int c = w * 6 + i;                     // 0..23
        int isA = c < 8;
        int cb = isA ? c : c - 8;
        int row = cb * 8 + (lane >> 3);
        int cg = (lane & 7) ^ (row & 7);       // XOR swizzle, global side
        gsrc[i] = (isA ? A + (size_t)(m0 + row) * K
                       : Bt + (size_t)(n0 + row) * K) + cg * 8;
        ldst[i] = (isA ? As : Bs) + cb * 512;
        nboff[i] = isA ? 4096 : 8192;
    }

    int wm = w & 1, wn = w >> 1;               // 2x2 waves, 32x64 each
    f32x4 acc[2][4];
#pragma unroll
    for (int mt = 0; mt < 2; ++mt)
#pragma unroll
        for (int nt = 0; nt < 4; ++nt)
            acc[mt][nt] = (f32x4){0.f, 0.f, 0.f, 0.f};

    int aoff[2][2], boff[4][2];
#pragma unroll
    for (int t = 0; t < 2; ++t) {
        int ar = wm * 32 + t * 16 + l15;
#pragma unroll
        for (int h = 0; h < 2; ++h)
            aoff[t][h] = ar * 64 + (((h * 4 + qd) ^ (ar & 7)) * 8);
    }
#pragma unroll
    for (int t = 0; t < 4; ++t) {
        int br = wn * 64 + t * 16 + l15;
#pragma unroll
        for (int h = 0; h < 2; ++h)
            boff[t][h] = br * 64 + (((h * 4 + qd) ^ (br & 7)) * 8);
    }

    // prologue: stage step 0 into buffer 0
#pragma unroll
    for (int i = 0; i < 6; ++i)
        __builtin_amdgcn_global_load_lds(
            (__attribute__((address_space(1))) void*)(gsrc[i]),
            (__attribute__((address_space(3))) void*)(ldst[i]), 16, 0, 0);

    int nsteps = K >> 6;                       // 16 or 48, always even

#define TSTEP64(S, RB)                                                      \
    {                                                                       \
        WAIT_VMCNT0();                                                      \
        __builtin_amdgcn_s_barrier();                                       \
        if ((S) + 1 < nsteps) {                                             \
            int k0 = ((S) + 1) << 6;                                        \
            _Pragma("unroll")                                               \
            for (int i = 0; i < 6; ++i)                                     \
                __builtin_amdgcn_global_load_lds(                           \
                    (__attribute__((address_space(1))) void*)(gsrc[i] + k0),\
                    (__attribute__((address_space(3))) void*)(ldst[i] +     \
                        (1 - (RB)) * nboff[i]),                             \
                    16, 0, 0);                                              \
        }                                                                   \
        bf16x8 av[2][2], bv[4][2];                                          \
        _Pragma("unroll")                                                   \
        for (int t = 0; t < 2; ++t)                                         \
            _Pragma("unroll")                                               \
            for (int h = 0; h < 2; ++h)                                     \
                av[t][h] = *(const bf16x8*)&As[aoff[t][h] + (RB) * 4096];   \
        _Pragma("unroll")                                                   \
        for (int t = 0; t < 4; ++t)                                         \
            _Pragma("unroll")                                               \
            for (int h = 0; h < 2; ++h)                                     \
                bv[t][h] = *(const bf16x8*)&Bs[boff[t][h] + (RB) * 8192];   \
        _Pragma("unroll")                                                   \
        for (int mt = 0; mt < 2; ++mt)                                      \
            _Pragma("unroll")                                               \
            for (int nt = 0; nt < 4; ++nt) {                                \
                acc[mt][nt] = __builtin_amdgcn_mfma_f32_16x16x32_bf16(      \
                    av[mt][0], bv[nt][0], acc[mt][nt], 0, 0, 0);            \
                acc[mt][nt] = __builtin_amdgcn_mfma_f32_16x16x32_bf16(      \
                    av[mt][1], bv[nt][1], acc[mt][nt], 0, 0, 0);            \
            }                                                               \
    }

    for (int s = 0; s < nsteps; s += 2) {
        TSTEP64(s, 0);
        TSTEP64(s + 1, 1);
    }

#pragma unroll
    for (int mt = 0; mt < 2; ++mt) {
        int row0 = m0 + wm * 32 + mt * 16 + qd * 4;
#pragma unroll
        for (int nt = 0; nt < 4; ++nt) {
            int col = n0 + wn * 64 + nt * 16 + l15;
#pragma unroll
            for (int reg = 0; reg < 4; ++reg) {
                float v = acc[mt][nt][reg] + bias[col]
                        + resid[(size_t)(row0 + reg) * ldc + col];
                C[(size_t)(row0 + reg) * ldc + col] = v;
            }
        }
    }
}

// ---------------------------------------------------------------- attention
// Flash-style MFMA; one wave per 16-query tile; <=5 chunks of 32 keys.
// qk buffer layout (bf16): [b, s, {q:0..1023, k:1024..2047}]
__global__ __launch_bounds__(256) void attn_k(
        const u16* __restrict__ qk, const u16* __restrict__ vt,
        u16* __restrict__ ctx) {
    int lane = threadIdx.x & 63, l15 = lane & 15, quad = lane >> 4;
    int t = blockIdx.x * 4 + (threadIdx.x >> 6);
    int qt = t & (SEQ / 16 - 1);
    int h  = (t >> 7) & (NH - 1);
    int b  = t >> 11;
    int q0 = qt * 16;
    int bh = b * NH + h;

    const u16* qrow = qk + (size_t)(b * SEQ + q0 + l15) * (2 * D_MODEL) + h * DH + quad * 8;
    bf16x8 qf0 = *(const bf16x8*)(qrow);
    bf16x8 qf1 = *(const bf16x8*)(qrow + 32);
    const u16* kbase = qk + (size_t)(b * SEQ) * (2 * D_MODEL) + D_MODEL + h * DH + quad * 8;
    const u16* vbase = vt + (size_t)(bh * DH) * SEQ;

    f32x4 o[4] = {{0.f, 0.f, 0.f, 0.f}, {0.f, 0.f, 0.f, 0.f},
                  {0.f, 0.f, 0.f, 0.f}, {0.f, 0.f, 0.f, 0.f}};
    float m = -1e30f, l = 0.f;
    int q = q0 + l15;
    int cs = q0 - (WIN - 1);
    cs = cs < 0 ? 0 : (cs & ~31);

    for (int c = cs; c <= q0 + 15; c += 32) {
        const u16* k0p = kbase + (size_t)(c + l15) * (2 * D_MODEL);
        const u16* k1p = k0p + (size_t)16 * (2 * D_MODEL);
        bf16x8 ka0 = *(const bf16x8*)(k0p);
        bf16x8 ka1 = *(const bf16x8*)(k0p + 32);
        bf16x8 kb0 = *(const bf16x8*)(k1p);
        bf16x8 kb1 = *(const bf16x8*)(k1p + 32);
        f32x4 s0 = {0.f, 0.f, 0.f, 0.f}, s1 = {0.f, 0.f, 0.f, 0.f};
        s0 = __builtin_amdgcn_mfma_f32_16x16x32_bf16(ka0, qf0, s0, 0, 0, 0);
        s0 = __builtin_amdgcn_mfma_f32_16x16x32_bf16(ka1, qf1, s0, 0, 0, 0);
        s1 = __builtin_amdgcn_mfma_f32_16x16x32_bf16(kb0, qf0, s1, 0, 0, 0);
        s1 = __builtin_amdgcn_mfma_f32_16x16x32_bf16(kb1, qf1, s1, 0, 0, 0);

        float p0[4], p1[4];
        float cm = -1e30f;
#pragma unroll
        for (int reg = 0; reg < 4; ++reg) {
            int k0i = c + quad * 4 + reg;
            p0[reg] = ((unsigned)(q - k0i) < WIN) ? s0[reg] * 0.125f : -1e30f;
            p1[reg] = ((unsigned)(q - k0i - 16) < WIN) ? s1[reg] * 0.125f : -1e30f;
            cm = fmaxf(cm, fmaxf(p0[reg], p1[reg]));
        }
        cm = fmaxf(cm, __shfl_xor(cm, 16, 64));
        cm = fmaxf(cm, __shfl_xor(cm, 32, 64));
        float mn = fmaxf(m, cm);
        float alpha = __expf(m - mn);
        m = mn;
        float ls = 0.f;
#pragma unroll
        for (int reg = 0; reg < 4; ++reg) {
            p0[reg] = __expf(p0[reg] - mn);
            p1[reg] = __expf(p1[reg] - mn);
            ls += p0[reg] + p1[reg];
        }
        ls += __shfl_xor(ls, 16, 64);
        ls += __shfl_xor(ls, 32, 64);
        l = l * alpha + ls;
#pragma unroll
        for (int mt = 0; mt < 4; ++mt) o[mt] *= alpha;

        u32 z0 = pk2(p0[0], p0[1]), z1 = pk2(p0[2], p0[3]);
        u32 w0 = pk2(p1[0], p1[1]), w1 = pk2(p1[2], p1[3]);
        int slo = ((quad & 1) * 2) * 16 + l15;
        int shi = slo + 16;
        u32 zl0 = (u32)__shfl((int)z0, slo, 64), zl1 = (u32)__shfl((int)z1, slo, 64);
        u32 zh0 = (u32)__shfl((int)z0, shi, 64), zh1 = (u32)__shfl((int)z1, shi, 64);
        u32 wl0 = (u32)__shfl((int)w0, slo, 64), wl1 = (u32)__shfl((int)w1, slo, 64);
        u32 wh0 = (u32)__shfl((int)w0, shi, 64), wh1 = (u32)__shfl((int)w1, shi, 64);
        alignas(16) u32 pr[4];
        pr[0] = quad < 2 ? zl0 : wl0;
        pr[1] = quad < 2 ? zl1 : wl1;
        pr[2] = quad < 2 ? zh0 : wh0;
        pr[3] = quad < 2 ? zh1 : wh1;
        bf16x8 pf = *(const bf16x8*)pr;

#pragma unroll
        for (int mt = 0; mt < 4; ++mt) {
            bf16x8 vf = *(const bf16x8*)(vbase + (size_t)(mt * 16 + l15) * SEQ + c + quad * 8);
            o[mt] = __builtin_amdgcn_mfma_f32_16x16x32_bf16(vf, pf, o[mt], 0, 0, 0);
        }
    }

    float rdiv = 1.f / l;
    u16* crow = ctx + (size_t)(b * SEQ + q0 + l15) * D_MODEL + h * DH;
#pragma unroll
    for (int mt = 0; mt < 4; ++mt) {
        ushort4 pkv = {f2b(o[mt][0] * rdiv), f2b(o[mt][1] * rdiv),
                       f2b(o[mt][2] * rdiv), f2b(o[mt][3] * rdiv)};
        *(ushort4*)(crow + mt * 16 + quad * 4) = pkv;
    }
}

// ---------------------------------------------------------------- launch
extern "C" void kernel_launch(void* const* d_in, const int* in_sizes, int n_in,
                              void* d_out, int out_size, void* d_ws, size_t ws_size,
                              hipStream_t stream) {
    (void)in_sizes; (void)n_in; (void)out_size; (void)ws_size;
    const float* x     = (const float*)d_in[0];
    const float* w_qkv = (const float*)d_in[1];
    const float* b_qkv = (const float*)d_in[2];
    const float* w_out = (const float*)d_in[3];
    const float* b_out = (const float*)d_in[4];
    const float* w_ff1 = (const float*)d_in[5];
    const float* b_ff1 = (const float*)d_in[6];
    const float* w_ff2 = (const float*)d_in[7];
    const float* b_ff2 = (const float*)d_in[8];
    const float* ln1g  = (const float*)d_in[9];
    const float* ln1b  = (const float*)d_in[10];
    const float* ln2g  = (const float*)d_in[11];
    const float* ln2b  = (const float*)d_in[12];
    float* out = (float*)d_out;

    const int M = BATCH * SEQ;                       // 4096
    char* base = (char*)d_ws;                        // 76 MiB peak
    u16*   hbf   = (u16*)(base);                     //  8 MiB: LN out
    u16*   qkbuf = (u16*)(base + (8ll  << 20));      // 16 MiB: Q,K [b,s,2048]
    u16*   ctxbf = (u16*)(base + (24ll << 20));      //  8 MiB: attn out
    u16*   vtbuf = (u16*)(base + (32ll << 20));      //  8 MiB: V^T [bh][d][s]
    u16*   ffbf  = (u16*)(base + (8ll  << 20));      // 24 MiB: FF inter (overlays qk+ctx, disjoint lifetime)
    float* x2    = (float*)(base + (40ll << 20));    // 16 MiB: f32 residual
    u16*   wqkvT = (u16*)(base + (56ll << 20));      //  6 MiB
    u16*   woutT = (u16*)(base + (62ll << 20));      //  2 MiB
    u16*   wff1T = (u16*)(base + (64ll << 20));      //  6 MiB
    u16*   wff2T = (u16*)(base + (70ll << 20));      //  6 MiB

    // fused: 4 weight transposes + LN1 (all independent)
    prep_k<<<dim3(14336), 256, 0, stream>>>(
        x, ln1g, ln1b, hbf, w_qkv, wqkvT, w_out, woutT,
        w_ff1, wff1T, w_ff2, wff2T);
    // QKV: Q,K -> qkbuf (ldc 2048); V -> vtbuf transposed. 128x64, 1536 blk.
    gemm3_k<0, 1><<<dim3((M / 128) * (3 * D_MODEL / 64)), 256, 0, stream>>>(
        hbf, wqkvT, b_qkv, qkbuf, vtbuf, M, 3 * D_MODEL, D_MODEL, 2 * D_MODEL);
    attn_k<<<dim3(BATCH * NH * (SEQ / 16) / 4), 256, 0, stream>>>(qkbuf, vtbuf, ctxbf);
    // x2 = x + ctx @ w_out + b_out   (64x128 tile, 512 blocks)
    gemm_tall_k<<<dim3(512), 256, 0, stream>>>(
        ctxbf, woutT, b_out, x, x2, M, D_MODEL, D_MODEL, D_MODEL);
    // hbf = bf16(LN2(x2))
    ln_k<<<M, 256, 0, stream>>>(x2, ln2g, ln2b, hbf);
    // ffbf = bf16(gelu(hbf @ w_ff1 + b_ff1))   (128x64, 1536 blocks)
    gemm3_k<1, 0><<<dim3((M / 128) * (DFF / 64)), 256, 0, stream>>>(
        hbf, wff1T, b_ff1, ffbf, nullptr, M, DFF, D_MODEL, DFF);
    // out = x2 + ffbf @ w_ff2 + b_ff2   (64x128 tile, 512 blocks)
    gemm_tall_k<<<dim3(512), 256, 0, stream>>>(
        ffbf, wff2T, b_ff2, x2, out, M, D_MODEL, DFF, D_MODEL);
}

// Round 6
// 272.621 us; speedup vs baseline: 1.0019x; 1.0019x over previous
//
#include <hip/hip_runtime.h>

#define D_MODEL 1024
#define SEQ 2048
#define BATCH 2
#define NH 16
#define DH 64
#define WIN 128
#define DFF 3072

typedef __bf16 bf16x8 __attribute__((ext_vector_type(8)));
typedef float f32x4 __attribute__((ext_vector_type(4)));
typedef unsigned short u16;
typedef unsigned int u32;

__device__ __forceinline__ float b2f(u16 u) {
    unsigned int x = ((unsigned int)u) << 16;
    return __uint_as_float(x);
}
__device__ __forceinline__ u16 f2b(float f) {
    unsigned int x = __float_as_uint(f);
    x += 0x7fffu + ((x >> 16) & 1u);
    return (u16)(x >> 16);
}
__device__ __forceinline__ u32 pk2(float a, float b) {
    return (u32)f2b(a) | ((u32)f2b(b) << 16);
}

// s_waitcnt imm: vmcnt[3:0]|[15:14], exp[6:4], lgkm[11:8].
// vmcnt(0), no exp/lgkm wait: 0x0F70. vmcnt(6): 0x0F76.
#define WAIT_VMCNT0() __builtin_amdgcn_s_waitcnt(0x0F70)
#define WAIT_VMCNT6() __builtin_amdgcn_s_waitcnt(0x0F76)

// ---------------------------------------------------------------- prep
// Fused: 4 weight transposes (f32 -> bf16, [K][N] -> [N][K]) + LN1.
// All parts independent, disjoint outputs; block-uniform branch on bid.
__global__ __launch_bounds__(256) void prep_k(
        const float* __restrict__ x, const float* __restrict__ g1,
        const float* __restrict__ bt1, u16* __restrict__ hbf,
        const float* __restrict__ wqkv, u16* __restrict__ wqkvT,
        const float* __restrict__ wout, u16* __restrict__ woutT,
        const float* __restrict__ wff1, u16* __restrict__ wff1T,
        const float* __restrict__ wff2, u16* __restrict__ wff2T) {
    __shared__ u16 tile[32][33];
    __shared__ float s1[4], s2[4];
    int bid = blockIdx.x;
    if (bid < 10240) {
        const float* in; u16* out; int R, C, loc, gx;
        if (bid < 3072)      { in = wqkv; out = wqkvT; R = 1024; C = 3072; loc = bid;        gx = 96; }
        else if (bid < 4096) { in = wout; out = woutT; R = 1024; C = 1024; loc = bid - 3072; gx = 32; }
        else if (bid < 7168) { in = wff1; out = wff1T; R = 1024; C = 3072; loc = bid - 4096; gx = 96; }
        else                 { in = wff2; out = wff2T; R = 3072; C = 1024; loc = bid - 7168; gx = 32; }
        int bx = loc % gx, by = loc / gx;
        int tx = threadIdx.x & 31, ty = threadIdx.x >> 5;
        int r0 = by * 32, c0 = bx * 32;
#pragma unroll
        for (int i = 0; i < 4; ++i)
            tile[ty + i * 8][tx] = f2b(in[(size_t)(r0 + ty + i * 8) * C + c0 + tx]);
        __syncthreads();
#pragma unroll
        for (int i = 0; i < 4; ++i)
            out[(size_t)(c0 + ty + i * 8) * R + r0 + tx] = tile[tx][ty + i * 8];
    } else {
        int row = bid - 10240;
        const float* xr = x + (size_t)row * D_MODEL;
        float v[4];
        float sum = 0.f, sq = 0.f;
#pragma unroll
        for (int i = 0; i < 4; ++i) {
            v[i] = xr[threadIdx.x + i * 256];
            sum += v[i];
            sq += v[i] * v[i];
        }
#pragma unroll
        for (int off = 32; off > 0; off >>= 1) {
            sum += __shfl_xor(sum, off, 64);
            sq  += __shfl_xor(sq, off, 64);
        }
        int w = threadIdx.x >> 6;
        if ((threadIdx.x & 63) == 0) { s1[w] = sum; s2[w] = sq; }
        __syncthreads();
        sum = s1[0] + s1[1] + s1[2] + s1[3];
        sq  = s2[0] + s2[1] + s2[2] + s2[3];
        float mu = sum * (1.f / D_MODEL);
        float var = sq * (1.f / D_MODEL) - mu * mu;
        float rstd = rsqrtf(var + 1e-5f);
        u16* outr = hbf + (size_t)row * D_MODEL;
#pragma unroll
        for (int i = 0; i < 4; ++i) {
            int c = threadIdx.x + i * 256;
            outr[c] = f2b((v[i] - mu) * rstd * g1[c] + bt1[c]);
        }
    }
}

// ---------------------------------------------------------------- layernorm
__global__ __launch_bounds__(256) void ln_k(
        const float* __restrict__ x, const float* __restrict__ g,
        const float* __restrict__ bta, u16* __restrict__ out) {
    int row = blockIdx.x;
    const float* xr = x + (size_t)row * D_MODEL;
    float v[4];
    float sum = 0.f, sq = 0.f;
#pragma unroll
    for (int i = 0; i < 4; ++i) {
        v[i] = xr[threadIdx.x + i * 256];
        sum += v[i];
        sq += v[i] * v[i];
    }
#pragma unroll
    for (int off = 32; off > 0; off >>= 1) {
        sum += __shfl_xor(sum, off, 64);
        sq  += __shfl_xor(sq, off, 64);
    }
    __shared__ float s1[4], s2[4];
    int w = threadIdx.x >> 6;
    if ((threadIdx.x & 63) == 0) { s1[w] = sum; s2[w] = sq; }
    __syncthreads();
    sum = s1[0] + s1[1] + s1[2] + s1[3];
    sq  = s2[0] + s2[1] + s2[2] + s2[3];
    float mu = sum * (1.f / D_MODEL);
    float var = sq * (1.f / D_MODEL) - mu * mu;
    float rstd = rsqrtf(var + 1e-5f);
    u16* outr = out + (size_t)row * D_MODEL;
#pragma unroll
    for (int i = 0; i < 4; ++i) {
        int c = threadIdx.x + i * 256;
        outr[c] = f2b((v[i] - mu) * rstd * g[c] + bta[c]);
    }
}

// ---------------------------------------------------------------- GEMM 128x64
// For QKV/FF1 (N=3072). R6: TRIPLE-buffered LDS (72 KiB -> 2 blocks/CU),
// depth-2 prefetch with counted vmcnt(6): at step s the wait covers loads
// issued at step s-2 (~700 cyc of latency cover vs ~350 with dbuf). The 6
// chunk-DMAs of step s+1 stay in flight across the barrier; vmcnt(0) only
// at the last step. Buffer (s+2)%3 written at step s was last read at step
// s-1 (readers done before this step's barrier) -> race-free. XOR bank
// swizzle unchanged (conflicts=0). Per-wave 64x32, acc[4][2].
template <int GELU, int VSPLIT>
__global__ __launch_bounds__(256, 2) void gemm3_k(
        const u16* __restrict__ A, const u16* __restrict__ Bt,
        const float* __restrict__ bias, u16* __restrict__ Cb,
        u16* __restrict__ vt, int M, int N, int K, int ldc) {
    __shared__ u16 As[3 * 128 * 64];           // 48 KiB
    __shared__ u16 Bs[3 * 64 * 64];            // 24 KiB
    int tid = threadIdx.x;
    int w = tid >> 6, lane = tid & 63;
    int qd = lane >> 4, l15 = lane & 15;

    // grid = (M/128)*(N/64) = 32*48 = 1536. XCD-stripe: 4 m-tiles per XCD
    // (512-row, 1 MiB A stripe stays L2-local per XCD).
    int lin = blockIdx.x;
    int xcd = lin & 7, idx = lin >> 3;         // idx 0..191
    int m0 = (xcd * 4 + (idx & 3)) * 128;
    int n0 = (idx >> 2) * 64;

    // Staging: 24 chunks of 1 KiB (8 rows x 64 cols); wave owns 6.
    // chunks 0-15 = A (128 rows), 16-23 = B (64 rows).
    const u16* gsrc[6];
    u16* ldst[6];
    int shr[6];                                // buf-offset shift: A=0, B=1
#pragma unroll
    for (int i = 0; i < 6; ++i) {
        int c = w * 6 + i;                     // 0..23
        int isA = c < 16;
        int cb = isA ? c : c - 16;
        int row = cb * 8 + (lane >> 3);
        int cg = (lane & 7) ^ (row & 7);       // XOR swizzle, global side
        gsrc[i] = (isA ? A + (size_t)(m0 + row) * K
                       : Bt + (size_t)(n0 + row) * K) + cg * 8;
        ldst[i] = (isA ? As : Bs) + cb * 512;
        shr[i] = isA ? 0 : 1;                  // B buffer stride = A/2
    }

    int wm = w & 1, wn = w >> 1;               // 2x2 waves, 64x32 each
    f32x4 acc[4][2];
#pragma unroll
    for (int mt = 0; mt < 4; ++mt)
#pragma unroll
        for (int nt = 0; nt < 2; ++nt)
            acc[mt][nt] = (f32x4){0.f, 0.f, 0.f, 0.f};

    int aoff[4][2], boff[2][2];
#pragma unroll
    for (int t = 0; t < 4; ++t) {
        int ar = wm * 64 + t * 16 + l15;
#pragma unroll
        for (int h = 0; h < 2; ++h)
            aoff[t][h] = ar * 64 + (((h * 4 + qd) ^ (ar & 7)) * 8);
    }
#pragma unroll
    for (int t = 0; t < 2; ++t) {
        int br = wn * 32 + t * 16 + l15;
#pragma unroll
        for (int h = 0; h < 2; ++h)
            boff[t][h] = br * 64 + (((h * 4 + qd) ^ (br & 7)) * 8);
    }

    // prologue: stage step 0 -> buf 0, step 1 -> buf 1 (12 DMAs in flight)
#pragma unroll
    for (int i = 0; i < 6; ++i)
        __builtin_amdgcn_global_load_lds(
            (__attribute__((address_space(1))) void*)(gsrc[i]),
            (__attribute__((address_space(3))) void*)(ldst[i]), 16, 0, 0);
#pragma unroll
    for (int i = 0; i < 6; ++i)
        __builtin_amdgcn_global_load_lds(
            (__attribute__((address_space(1))) void*)(gsrc[i] + 64),
            (__attribute__((address_space(3))) void*)(ldst[i] + (8192 >> shr[i])),
            16, 0, 0);

    int nsteps = K >> 6;                       // 16 (K=1024), >= 3
    int curA = 0;                              // A elem-offset of current buf
    int pfA = 2 * 8192;                        // A elem-offset of buf s+2

    for (int s = 0; s < nsteps; ++s) {
        if (s + 1 < nsteps) WAIT_VMCNT6();     // own buf-s DMAs done;
        else                WAIT_VMCNT0();     //   buf-(s+1)'s stay in flight
        __builtin_amdgcn_s_barrier();          // all waves' buf-s DMAs landed
        if (s + 2 < nsteps) {                  // wave-uniform
            int k0 = (s + 2) << 6;
#pragma unroll
            for (int i = 0; i < 6; ++i)
                __builtin_amdgcn_global_load_lds(
                    (__attribute__((address_space(1))) void*)(gsrc[i] + k0),
                    (__attribute__((address_space(3))) void*)(ldst[i] + (pfA >> shr[i])),
                    16, 0, 0);
        }
        int curB = curA >> 1;
        bf16x8 av[4][2], bv[2][2];
#pragma unroll
        for (int t = 0; t < 4; ++t)
#pragma unroll
            for (int h = 0; h < 2; ++h)
                av[t][h] = *(const bf16x8*)&As[aoff[t][h] + curA];
#pragma unroll
        for (int t = 0; t < 2; ++t)
#pragma unroll
            for (int h = 0; h < 2; ++h)
                bv[t][h] = *(const bf16x8*)&Bs[boff[t][h] + curB];
#pragma unroll
        for (int mt = 0; mt < 4; ++mt)
#pragma unroll
            for (int nt = 0; nt < 2; ++nt) {
                acc[mt][nt] = __builtin_amdgcn_mfma_f32_16x16x32_bf16(
                    av[mt][0], bv[nt][0], acc[mt][nt], 0, 0, 0);
                acc[mt][nt] = __builtin_amdgcn_mfma_f32_16x16x32_bf16(
                    av[mt][1], bv[nt][1], acc[mt][nt], 0, 0, 0);
            }
        curA += 8192; if (curA == 3 * 8192) curA = 0;
        pfA  += 8192; if (pfA  == 3 * 8192) pfA  = 0;
    }

#pragma unroll
    for (int mt = 0; mt < 4; ++mt) {
        int row0 = m0 + wm * 64 + mt * 16 + qd * 4;
#pragma unroll
        for (int nt = 0; nt < 2; ++nt) {
            int col = n0 + wn * 32 + nt * 16 + l15;
            float v[4];
#pragma unroll
            for (int reg = 0; reg < 4; ++reg) {
                v[reg] = acc[mt][nt][reg] + bias[col];
                if (GELU) v[reg] = 0.5f * v[reg] * (1.f + erff(v[reg] * 0.70710678118654752f));
            }
            if (VSPLIT && col >= 2 * D_MODEL) {
                int d = col - 2 * D_MODEL;
                int bh = (row0 >> 11) * NH + (d >> 6);
                ushort4 pkv = {f2b(v[0]), f2b(v[1]), f2b(v[2]), f2b(v[3])};
                *(ushort4*)&vt[((size_t)(bh * DH + (d & 63))) * SEQ + (row0 & (SEQ - 1))] = pkv;
            } else {
#pragma unroll
                for (int reg = 0; reg < 4; ++reg)
                    Cb[(size_t)(row0 + reg) * ldc + col] = f2b(v[reg]);
            }
        }
    }
}

// ---------------------------------------------------------------- GEMM 64x128
// For the N=1024 GEMMs (attn-out, FF2). Grid = 512 blocks, 48 KiB LDS ->
// 3 blocks/CU. Always: bias + resid + f32 out. Per-wave 32x64, acc[2][4].
__global__ __launch_bounds__(256, 3) void gemm_tall_k(
        const u16* __restrict__ A, const u16* __restrict__ Bt,
        const float* __restrict__ bias, const float* __restrict__ resid,
        float* __restrict__ C, int M, int N, int K, int ldc) {
    __shared__ u16 As[2 * 64 * 64];            // 16 KiB
    __shared__ u16 Bs[2 * 128 * 64];           // 32 KiB
    int tid = threadIdx.x;
    int w = tid >> 6, lane = tid & 63;
    int qd = lane >> 4, l15 = lane & 15;

    // grid = (M/64)*(N/128) = 64*8 = 512. XCD-stripe: 8 m-tiles per XCD.
    int lin = blockIdx.x;
    int xcd = lin & 7, idx = lin >> 3;         // idx 0..63
    int m0 = (xcd * 8 + (idx & 7)) * 64;
    int n0 = (idx >> 3) * 128;

    // Staging: 24 chunks of 1 KiB (8 rows x 64 cols); wave owns 6.
    // chunks 0-7 = A (64 rows), 8-23 = B (128 rows).
    const u16* gsrc[6];
    u16* ldst[6];
    int nboff[6];                              // elem offset to buffer 1
#pragma unroll
    for (int i = 0; i < 6; ++i) {
        int c = w * 6 + i;                     // 0..23
        int isA = c < 8;
        int cb = isA ? c : c - 8;
        int row = cb * 8 + (lane >> 3);
        int cg = (lane & 7) ^ (row & 7);       // XOR swizzle, global side
        gsrc[i] = (isA ? A + (size_t)(m0 + row) * K
                       : Bt + (size_t)(n0 + row) * K) + cg * 8;
        ldst[i] = (isA ? As : Bs) + cb * 512;
        nboff[i] = isA ? 4096 : 8192;
    }

    int wm = w & 1, wn = w >> 1;               // 2x2 waves, 32x64 each
    f32x4 acc[2][4];
#pragma unroll
    for (int mt = 0; mt < 2; ++mt)
#pragma unroll
        for (int nt = 0; nt < 4; ++nt)
            acc[mt][nt] = (f32x4){0.f, 0.f, 0.f, 0.f};

    int aoff[2][2], boff[4][2];
#pragma unroll
    for (int t = 0; t < 2; ++t) {
        int ar = wm * 32 + t * 16 + l15;
#pragma unroll
        for (int h = 0; h < 2; ++h)
            aoff[t][h] = ar * 64 + (((h * 4 + qd) ^ (ar & 7)) * 8);
    }
#pragma unroll
    for (int t = 0; t < 4; ++t) {
        int br = wn * 64 + t * 16 + l15;
#pragma unroll
        for (int h = 0; h < 2; ++h)
            boff[t][h] = br * 64 + (((h * 4 + qd) ^ (br & 7)) * 8);
    }

    // prologue: stage step 0 into buffer 0
#pragma unroll
    for (int i = 0; i < 6; ++i)
        __builtin_amdgcn_global_load_lds(
            (__attribute__((address_space(1))) void*)(gsrc[i]),
            (__attribute__((address_space(3))) void*)(ldst[i]), 16, 0, 0);

    int nsteps = K >> 6;                       // 16 or 48, always even

#define TSTEP64(S, RB)                                                      \
    {                                                                       \
        WAIT_VMCNT0();                                                      \
        __builtin_amdgcn_s_barrier();                                       \
        if ((S) + 1 < nsteps) {                                             \
            int k0 = ((S) + 1) << 6;                                        \
            _Pragma("unroll")                                               \
            for (int i = 0; i < 6; ++i)                                     \
                __builtin_amdgcn_global_load_lds(                           \
                    (__attribute__((address_space(1))) void*)(gsrc[i] + k0),\
                    (__attribute__((address_space(3))) void*)(ldst[i] +     \
                        (1 - (RB)) * nboff[i]),                             \
                    16, 0, 0);                                              \
        }                                                                   \
        bf16x8 av[2][2], bv[4][2];                                          \
        _Pragma("unroll")                                                   \
        for (int t = 0; t < 2; ++t)                                         \
            _Pragma("unroll")                                               \
            for (int h = 0; h < 2; ++h)                                     \
                av[t][h] = *(const bf16x8*)&As[aoff[t][h] + (RB) * 4096];   \
        _Pragma("unroll")                                                   \
        for (int t = 0; t < 4; ++t)                                         \
            _Pragma("unroll")                                               \
            for (int h = 0; h < 2; ++h)                                     \
                bv[t][h] = *(const bf16x8*)&Bs[boff[t][h] + (RB) * 8192];   \
        _Pragma("unroll")                                                   \
        for (int mt = 0; mt < 2; ++mt)                                      \
            _Pragma("unroll")                                               \
            for (int nt = 0; nt < 4; ++nt) {                                \
                acc[mt][nt] = __builtin_amdgcn_mfma_f32_16x16x32_bf16(      \
                    av[mt][0], bv[nt][0], acc[mt][nt], 0, 0, 0);            \
                acc[mt][nt] = __builtin_amdgcn_mfma_f32_16x16x32_bf16(      \
                    av[mt][1], bv[nt][1], acc[mt][nt], 0, 0, 0);            \
            }                                                               \
    }

    for (int s = 0; s < nsteps; s += 2) {
        TSTEP64(s, 0);
        TSTEP64(s + 1, 1);
    }

#pragma unroll
    for (int mt = 0; mt < 2; ++mt) {
        int row0 = m0 + wm * 32 + mt * 16 + qd * 4;
#pragma unroll
        for (int nt = 0; nt < 4; ++nt) {
            int col = n0 + wn * 64 + nt * 16 + l15;
#pragma unroll
            for (int reg = 0; reg < 4; ++reg) {
                float v = acc[mt][nt][reg] + bias[col]
                        + resid[(size_t)(row0 + reg) * ldc + col];
                C[(size_t)(row0 + reg) * ldc + col] = v;
            }
        }
    }
}

// ---------------------------------------------------------------- attention
// Flash-style MFMA; one wave per 16-query tile; <=5 chunks of 32 keys.
// qk buffer layout (bf16): [b, s, {q:0..1023, k:1024..2047}]
__global__ __launch_bounds__(256) void attn_k(
        const u16* __restrict__ qk, const u16* __restrict__ vt,
        u16* __restrict__ ctx) {
    int lane = threadIdx.x & 63, l15 = lane & 15, quad = lane >> 4;
    int t = blockIdx.x * 4 + (threadIdx.x >> 6);
    int qt = t & (SEQ / 16 - 1);
    int h  = (t >> 7) & (NH - 1);
    int b  = t >> 11;
    int q0 = qt * 16;
    int bh = b * NH + h;

    const u16* qrow = qk + (size_t)(b * SEQ + q0 + l15) * (2 * D_MODEL) + h * DH + quad * 8;
    bf16x8 qf0 = *(const bf16x8*)(qrow);
    bf16x8 qf1 = *(const bf16x8*)(qrow + 32);
    const u16* kbase = qk + (size_t)(b * SEQ) * (2 * D_MODEL) + D_MODEL + h * DH + quad * 8;
    const u16* vbase = vt + (size_t)(bh * DH) * SEQ;

    f32x4 o[4] = {{0.f, 0.f, 0.f, 0.f}, {0.f, 0.f, 0.f, 0.f},
                  {0.f, 0.f, 0.f, 0.f}, {0.f, 0.f, 0.f, 0.f}};
    float m = -1e30f, l = 0.f;
    int q = q0 + l15;
    int cs = q0 - (WIN - 1);
    cs = cs < 0 ? 0 : (cs & ~31);

    for (int c = cs; c <= q0 + 15; c += 32) {
        const u16* k0p = kbase + (size_t)(c + l15) * (2 * D_MODEL);
        const u16* k1p = k0p + (size_t)16 * (2 * D_MODEL);
        bf16x8 ka0 = *(const bf16x8*)(k0p);
        bf16x8 ka1 = *(const bf16x8*)(k0p + 32);
        bf16x8 kb0 = *(const bf16x8*)(k1p);
        bf16x8 kb1 = *(const bf16x8*)(k1p + 32);
        f32x4 s0 = {0.f, 0.f, 0.f, 0.f}, s1 = {0.f, 0.f, 0.f, 0.f};
        s0 = __builtin_amdgcn_mfma_f32_16x16x32_bf16(ka0, qf0, s0, 0, 0, 0);
        s0 = __builtin_amdgcn_mfma_f32_16x16x32_bf16(ka1, qf1, s0, 0, 0, 0);
        s1 = __builtin_amdgcn_mfma_f32_16x16x32_bf16(kb0, qf0, s1, 0, 0, 0);
        s1 = __builtin_amdgcn_mfma_f32_16x16x32_bf16(kb1, qf1, s1, 0, 0, 0);

        float p0[4], p1[4];
        float cm = -1e30f;
#pragma unroll
        for (int reg = 0; reg < 4; ++reg) {
            int k0i = c + quad * 4 + reg;
            p0[reg] = ((unsigned)(q - k0i) < WIN) ? s0[reg] * 0.125f : -1e30f;
            p1[reg] = ((unsigned)(q - k0i - 16) < WIN) ? s1[reg] * 0.125f : -1e30f;
            cm = fmaxf(cm, fmaxf(p0[reg], p1[reg]));
        }
        cm = fmaxf(cm, __shfl_xor(cm, 16, 64));
        cm = fmaxf(cm, __shfl_xor(cm, 32, 64));
        float mn = fmaxf(m, cm);
        float alpha = __expf(m - mn);
        m = mn;
        float ls = 0.f;
#pragma unroll
        for (int reg = 0; reg < 4; ++reg) {
            p0[reg] = __expf(p0[reg] - mn);
            p1[reg] = __expf(p1[reg] - mn);
            ls += p0[reg] + p1[reg];
        }
        ls += __shfl_xor(ls, 16, 64);
        ls += __shfl_xor(ls, 32, 64);
        l = l * alpha + ls;
#pragma unroll
        for (int mt = 0; mt < 4; ++mt) o[mt] *= alpha;

        u32 z0 = pk2(p0[0], p0[1]), z1 = pk2(p0[2], p0[3]);
        u32 w0 = pk2(p1[0], p1[1]), w1 = pk2(p1[2], p1[3]);
        int slo = ((quad & 1) * 2) * 16 + l15;
        int shi = slo + 16;
        u32 zl0 = (u32)__shfl((int)z0, slo, 64), zl1 = (u32)__shfl((int)z1, slo, 64);
        u32 zh0 = (u32)__shfl((int)z0, shi, 64), zh1 = (u32)__shfl((int)z1, shi, 64);
        u32 wl0 = (u32)__shfl((int)w0, slo, 64), wl1 = (u32)__shfl((int)w1, slo, 64);
        u32 wh0 = (u32)__shfl((int)w0, shi, 64), wh1 = (u32)__shfl((int)w1, shi, 64);
        alignas(16) u32 pr[4];
        pr[0] = quad < 2 ? zl0 : wl0;
        pr[1] = quad < 2 ? zl1 : wl1;
        pr[2] = quad < 2 ? zh0 : wh0;
        pr[3] = quad < 2 ? zh1 : wh1;
        bf16x8 pf = *(const bf16x8*)pr;

#pragma unroll
        for (int mt = 0; mt < 4; ++mt) {
            bf16x8 vf = *(const bf16x8*)(vbase + (size_t)(mt * 16 + l15) * SEQ + c + quad * 8);
            o[mt] = __builtin_amdgcn_mfma_f32_16x16x32_bf16(vf, pf, o[mt], 0, 0, 0);
        }
    }

    float rdiv = 1.f / l;
    u16* crow = ctx + (size_t)(b * SEQ + q0 + l15) * D_MODEL + h * DH;
#pragma unroll
    for (int mt = 0; mt < 4; ++mt) {
        ushort4 pkv = {f2b(o[mt][0] * rdiv), f2b(o[mt][1] * rdiv),
                       f2b(o[mt][2] * rdiv), f2b(o[mt][3] * rdiv)};
        *(ushort4*)(crow + mt * 16 + quad * 4) = pkv;
    }
}

// ---------------------------------------------------------------- launch
extern "C" void kernel_launch(void* const* d_in, const int* in_sizes, int n_in,
                              void* d_out, int out_size, void* d_ws, size_t ws_size,
                              hipStream_t stream) {
    (void)in_sizes; (void)n_in; (void)out_size; (void)ws_size;
    const float* x     = (const float*)d_in[0];
    const float* w_qkv = (const float*)d_in[1];
    const float* b_qkv = (const float*)d_in[2];
    const float* w_out = (const float*)d_in[3];
    const float* b_out = (const float*)d_in[4];
    const float* w_ff1 = (const float*)d_in[5];
    const float* b_ff1 = (const float*)d_in[6];
    const float* w_ff2 = (const float*)d_in[7];
    const float* b_ff2 = (const float*)d_in[8];
    const float* ln1g  = (const float*)d_in[9];
    const float* ln1b  = (const float*)d_in[10];
    const float* ln2g  = (const float*)d_in[11];
    const float* ln2b  = (const float*)d_in[12];
    float* out = (float*)d_out;

    const int M = BATCH * SEQ;                       // 4096
    char* base = (char*)d_ws;                        // 76 MiB peak
    u16*   hbf   = (u16*)(base);                     //  8 MiB: LN out
    u16*   qkbuf = (u16*)(base + (8ll  << 20));      // 16 MiB: Q,K [b,s,2048]
    u16*   ctxbf = (u16*)(base + (24ll << 20));      //  8 MiB: attn out
    u16*   vtbuf = (u16*)(base + (32ll << 20));      //  8 MiB: V^T [bh][d][s]
    u16*   ffbf  = (u16*)(base + (8ll  << 20));      // 24 MiB: FF inter (overlays qk+ctx, disjoint lifetime)
    float* x2    = (float*)(base + (40ll << 20));    // 16 MiB: f32 residual
    u16*   wqkvT = (u16*)(base + (56ll << 20));      //  6 MiB
    u16*   woutT = (u16*)(base + (62ll << 20));      //  2 MiB
    u16*   wff1T = (u16*)(base + (64ll << 20));      //  6 MiB
    u16*   wff2T = (u16*)(base + (70ll << 20));      //  6 MiB

    // fused: 4 weight transposes + LN1 (all independent)
    prep_k<<<dim3(14336), 256, 0, stream>>>(
        x, ln1g, ln1b, hbf, w_qkv, wqkvT, w_out, woutT,
        w_ff1, wff1T, w_ff2, wff2T);
    // QKV: Q,K -> qkbuf (ldc 2048); V -> vtbuf transposed. 128x64, 1536 blk.
    gemm3_k<0, 1><<<dim3((M / 128) * (3 * D_MODEL / 64)), 256, 0, stream>>>(
        hbf, wqkvT, b_qkv, qkbuf, vtbuf, M, 3 * D_MODEL, D_MODEL, 2 * D_MODEL);
    attn_k<<<dim3(BATCH * NH * (SEQ / 16) / 4), 256, 0, stream>>>(qkbuf, vtbuf, ctxbf);
    // x2 = x + ctx @ w_out + b_out   (64x128 tile, 512 blocks)
    gemm_tall_k<<<dim3(512), 256, 0, stream>>>(
        ctxbf, woutT, b_out, x, x2, M, D_MODEL, D_MODEL, D_MODEL);
    // hbf = bf16(LN2(x2))
    ln_k<<<M, 256, 0, stream>>>(x2, ln2g, ln2b, hbf);
    // ffbf = bf16(gelu(hbf @ w_ff1 + b_ff1))   (128x64, 1536 blocks)
    gemm3_k<1, 0><<<dim3((M / 128) * (DFF / 64)), 256, 0, stream>>>(
        hbf, wff1T, b_ff1, ffbf, nullptr, M, DFF, D_MODEL, DFF);
    // out = x2 + ffbf @ w_ff2 + b_ff2   (64x128 tile, 512 blocks)
    gemm_tall_k<<<dim3(512), 256, 0, stream>>>(
        ffbf, wff2T, b_ff2, x2, out, M, D_MODEL, DFF, D_MODEL);
}

// Round 7
// 267.978 us; speedup vs baseline: 1.0193x; 1.0173x over previous
//
#include <hip/hip_runtime.h>

#define D_MODEL 1024
#define SEQ 2048
#define BATCH 2
#define NH 16
#define DH 64
#define WIN 128
#define DFF 3072

typedef __bf16 bf16x8 __attribute__((ext_vector_type(8)));
typedef float f32x4 __attribute__((ext_vector_type(4)));
typedef unsigned short u16;
typedef unsigned int u32;

__device__ __forceinline__ float b2f(u16 u) {
    unsigned int x = ((unsigned int)u) << 16;
    return __uint_as_float(x);
}
__device__ __forceinline__ u16 f2b(float f) {
    unsigned int x = __float_as_uint(f);
    x += 0x7fffu + ((x >> 16) & 1u);
    return (u16)(x >> 16);
}
__device__ __forceinline__ u32 pk2(float a, float b) {
    return (u32)f2b(a) | ((u32)f2b(b) << 16);
}

// s_waitcnt imm: vmcnt[3:0]|[15:14], exp[6:4], lgkm[11:8]. vmcnt(0), no
// exp/lgkm wait: 0x0F70.
#define WAIT_VMCNT0() __builtin_amdgcn_s_waitcnt(0x0F70)

// ---------------------------------------------------------------- prep
// Fused: 4 weight transposes (f32 -> bf16, [R][C] -> [C][R]) + LN1.
// R7: 64x64 transpose tiles with ushort4 stores (16 consecutive lanes
// write 128B contiguous per output column; old 32x32 version did scalar
// u16 stores = 64B segments). Reads stay coalesced (64 lanes x 4B).
// Ranges: [0,768) wqkv, [768,1024) wout, [1024,1792) wff1,
//         [1792,2560) wff2, [2560,6656) LN1 rows.
__global__ __launch_bounds__(256) void prep_k(
        const float* __restrict__ x, const float* __restrict__ g1,
        const float* __restrict__ bt1, u16* __restrict__ hbf,
        const float* __restrict__ wqkv, u16* __restrict__ wqkvT,
        const float* __restrict__ wout, u16* __restrict__ woutT,
        const float* __restrict__ wff1, u16* __restrict__ wff1T,
        const float* __restrict__ wff2, u16* __restrict__ wff2T) {
    __shared__ u16 tile[64][65];
    __shared__ float s1[4], s2[4];
    int bid = blockIdx.x;
    int tid = threadIdx.x;
    if (bid < 2560) {
        const float* in; u16* out; int R, C, loc, gx;
        if (bid < 768)       { in = wqkv; out = wqkvT; R = 1024; C = 3072; loc = bid;        gx = 48; }
        else if (bid < 1024) { in = wout; out = woutT; R = 1024; C = 1024; loc = bid - 768;  gx = 16; }
        else if (bid < 1792) { in = wff1; out = wff1T; R = 1024; C = 3072; loc = bid - 1024; gx = 48; }
        else                 { in = wff2; out = wff2T; R = 3072; C = 1024; loc = bid - 1792; gx = 16; }
        int bx = loc % gx, by = loc / gx;
        int r0 = by * 64, c0 = bx * 64;
        int w = tid >> 6, cc = tid & 63;
#pragma unroll
        for (int i = 0; i < 16; ++i) {
            int r = i * 4 + w;
            tile[r][cc] = f2b(in[(size_t)(r0 + r) * C + c0 + cc]);
        }
        __syncthreads();
        int rr = (tid & 15) * 4;
        int cb = tid >> 4;                     // 0..15
#pragma unroll
        for (int j = 0; j < 4; ++j) {
            int c = cb + j * 16;
            ushort4 p = {tile[rr][c], tile[rr + 1][c],
                         tile[rr + 2][c], tile[rr + 3][c]};
            *(ushort4*)&out[(size_t)(c0 + c) * R + r0 + rr] = p;
        }
    } else {
        int row = bid - 2560;
        const float* xr = x + (size_t)row * D_MODEL;
        float v[4];
        float sum = 0.f, sq = 0.f;
#pragma unroll
        for (int i = 0; i < 4; ++i) {
            v[i] = xr[tid + i * 256];
            sum += v[i];
            sq += v[i] * v[i];
        }
#pragma unroll
        for (int off = 32; off > 0; off >>= 1) {
            sum += __shfl_xor(sum, off, 64);
            sq  += __shfl_xor(sq, off, 64);
        }
        int w = tid >> 6;
        if ((tid & 63) == 0) { s1[w] = sum; s2[w] = sq; }
        __syncthreads();
        sum = s1[0] + s1[1] + s1[2] + s1[3];
        sq  = s2[0] + s2[1] + s2[2] + s2[3];
        float mu = sum * (1.f / D_MODEL);
        float var = sq * (1.f / D_MODEL) - mu * mu;
        float rstd = rsqrtf(var + 1e-5f);
        u16* outr = hbf + (size_t)row * D_MODEL;
#pragma unroll
        for (int i = 0; i < 4; ++i) {
            int c = tid + i * 256;
            outr[c] = f2b((v[i] - mu) * rstd * g1[c] + bt1[c]);
        }
    }
}

// ---------------------------------------------------------------- layernorm
__global__ __launch_bounds__(256) void ln_k(
        const float* __restrict__ x, const float* __restrict__ g,
        const float* __restrict__ bta, u16* __restrict__ out) {
    int row = blockIdx.x;
    const float* xr = x + (size_t)row * D_MODEL;
    float v[4];
    float sum = 0.f, sq = 0.f;
#pragma unroll
    for (int i = 0; i < 4; ++i) {
        v[i] = xr[threadIdx.x + i * 256];
        sum += v[i];
        sq += v[i] * v[i];
    }
#pragma unroll
    for (int off = 32; off > 0; off >>= 1) {
        sum += __shfl_xor(sum, off, 64);
        sq  += __shfl_xor(sq, off, 64);
    }
    __shared__ float s1[4], s2[4];
    int w = threadIdx.x >> 6;
    if ((threadIdx.x & 63) == 0) { s1[w] = sum; s2[w] = sq; }
    __syncthreads();
    sum = s1[0] + s1[1] + s1[2] + s1[3];
    sq  = s2[0] + s2[1] + s2[2] + s2[3];
    float mu = sum * (1.f / D_MODEL);
    float var = sq * (1.f / D_MODEL) - mu * mu;
    float rstd = rsqrtf(var + 1e-5f);
    u16* outr = out + (size_t)row * D_MODEL;
#pragma unroll
    for (int i = 0; i < 4; ++i) {
        int c = threadIdx.x + i * 256;
        outr[c] = f2b((v[i] - mu) * rstd * g[c] + bta[c]);
    }
}

// ---------------------------------------------------------------- GEMM 128x64
// For QKV/FF1 (N=3072). R5-proven config (43.3 us, MfmaUtil 22.7%):
// 48 KiB LDS -> 3 blocks/CU (12 waves) so vmcnt stalls interleave across
// blocks; grid = 32x48 = 1536 = exactly 2 full co-residency rounds. 1
// vmcnt(0)+raw-barrier per K-step, dbuf, chunk staging with XOR bank
// swizzle (conflicts=0). Per-wave 64x32, acc[4][2].
// (R6 triple-buffer+vmcnt(6) regressed to 64 us: occupancy loss 3->2
// blocks/CU dominated the deeper pipeline. Wave-TLP is the lever here.)
template <int GELU, int VSPLIT>
__global__ __launch_bounds__(256, 3) void gemm3_k(
        const u16* __restrict__ A, const u16* __restrict__ Bt,
        const float* __restrict__ bias, u16* __restrict__ Cb,
        u16* __restrict__ vt, int M, int N, int K, int ldc) {
    __shared__ u16 As[2 * 128 * 64];           // 32 KiB
    __shared__ u16 Bs[2 * 64 * 64];            // 16 KiB
    int tid = threadIdx.x;
    int w = tid >> 6, lane = tid & 63;
    int qd = lane >> 4, l15 = lane & 15;

    // grid = (M/128)*(N/64) = 32*48 = 1536. XCD-stripe: 4 m-tiles per XCD
    // (512-row, 1 MiB A stripe stays L2-local per XCD).
    int lin = blockIdx.x;
    int xcd = lin & 7, idx = lin >> 3;         // idx 0..191
    int m0 = (xcd * 4 + (idx & 3)) * 128;
    int n0 = (idx >> 2) * 64;

    // Staging: 24 chunks of 1 KiB (8 rows x 64 cols); wave owns 6.
    // chunks 0-15 = A (128 rows), 16-23 = B (64 rows).
    const u16* gsrc[6];
    u16* ldst[6];
    int nboff[6];                              // elem offset to buffer 1
#pragma unroll
    for (int i = 0; i < 6; ++i) {
        int c = w * 6 + i;                     // 0..23
        int isA = c < 16;
        int cb = isA ? c : c - 16;
        int row = cb * 8 + (lane >> 3);
        int cg = (lane & 7) ^ (row & 7);       // XOR swizzle, global side
        gsrc[i] = (isA ? A + (size_t)(m0 + row) * K
                       : Bt + (size_t)(n0 + row) * K) + cg * 8;
        ldst[i] = (isA ? As : Bs) + cb * 512;
        nboff[i] = isA ? 8192 : 4096;
    }

    int wm = w & 1, wn = w >> 1;               // 2x2 waves, 64x32 each
    f32x4 acc[4][2];
#pragma unroll
    for (int mt = 0; mt < 4; ++mt)
#pragma unroll
        for (int nt = 0; nt < 2; ++nt)
            acc[mt][nt] = (f32x4){0.f, 0.f, 0.f, 0.f};

    int aoff[4][2], boff[2][2];
#pragma unroll
    for (int t = 0; t < 4; ++t) {
        int ar = wm * 64 + t * 16 + l15;
#pragma unroll
        for (int h = 0; h < 2; ++h)
            aoff[t][h] = ar * 64 + (((h * 4 + qd) ^ (ar & 7)) * 8);
    }
#pragma unroll
    for (int t = 0; t < 2; ++t) {
        int br = wn * 32 + t * 16 + l15;
#pragma unroll
        for (int h = 0; h < 2; ++h)
            boff[t][h] = br * 64 + (((h * 4 + qd) ^ (br & 7)) * 8);
    }

    // prologue: stage step 0 into buffer 0
#pragma unroll
    for (int i = 0; i < 6; ++i)
        __builtin_amdgcn_global_load_lds(
            (__attribute__((address_space(1))) void*)(gsrc[i]),
            (__attribute__((address_space(3))) void*)(ldst[i]), 16, 0, 0);

    int nsteps = K >> 6;                       // 16, even

#define TSTEP3(S, RB)                                                       \
    {                                                                       \
        WAIT_VMCNT0();                                                      \
        __builtin_amdgcn_s_barrier();                                       \
        if ((S) + 1 < nsteps) {                                             \
            int k0 = ((S) + 1) << 6;                                        \
            _Pragma("unroll")                                               \
            for (int i = 0; i < 6; ++i)                                     \
                __builtin_amdgcn_global_load_lds(                           \
                    (__attribute__((address_space(1))) void*)(gsrc[i] + k0),\
                    (__attribute__((address_space(3))) void*)(ldst[i] +     \
                        (1 - (RB)) * nboff[i]),                             \
                    16, 0, 0);                                              \
        }                                                                   \
        bf16x8 av[4][2], bv[2][2];                                          \
        _Pragma("unroll")                                                   \
        for (int t = 0; t < 4; ++t)                                         \
            _Pragma("unroll")                                               \
            for (int h = 0; h < 2; ++h)                                     \
                av[t][h] = *(const bf16x8*)&As[aoff[t][h] + (RB) * 8192];   \
        _Pragma("unroll")                                                   \
        for (int t = 0; t < 2; ++t)                                         \
            _Pragma("unroll")                                               \
            for (int h = 0; h < 2; ++h)                                     \
                bv[t][h] = *(const bf16x8*)&Bs[boff[t][h] + (RB) * 4096];   \
        _Pragma("unroll")                                                   \
        for (int mt = 0; mt < 4; ++mt)                                      \
            _Pragma("unroll")                                               \
            for (int nt = 0; nt < 2; ++nt) {                                \
                acc[mt][nt] = __builtin_amdgcn_mfma_f32_16x16x32_bf16(      \
                    av[mt][0], bv[nt][0], acc[mt][nt], 0, 0, 0);            \
                acc[mt][nt] = __builtin_amdgcn_mfma_f32_16x16x32_bf16(      \
                    av[mt][1], bv[nt][1], acc[mt][nt], 0, 0, 0);            \
            }                                                               \
    }

    for (int s = 0; s < nsteps; s += 2) {
        TSTEP3(s, 0);
        TSTEP3(s + 1, 1);
    }

#pragma unroll
    for (int mt = 0; mt < 4; ++mt) {
        int row0 = m0 + wm * 64 + mt * 16 + qd * 4;
#pragma unroll
        for (int nt = 0; nt < 2; ++nt) {
            int col = n0 + wn * 32 + nt * 16 + l15;
            float v[4];
#pragma unroll
            for (int reg = 0; reg < 4; ++reg) {
                v[reg] = acc[mt][nt][reg] + bias[col];
                if (GELU) v[reg] = 0.5f * v[reg] * (1.f + erff(v[reg] * 0.70710678118654752f));
            }
            if (VSPLIT && col >= 2 * D_MODEL) {
                int d = col - 2 * D_MODEL;
                int bh = (row0 >> 11) * NH + (d >> 6);
                ushort4 pkv = {f2b(v[0]), f2b(v[1]), f2b(v[2]), f2b(v[3])};
                *(ushort4*)&vt[((size_t)(bh * DH + (d & 63))) * SEQ + (row0 & (SEQ - 1))] = pkv;
            } else {
#pragma unroll
                for (int reg = 0; reg < 4; ++reg)
                    Cb[(size_t)(row0 + reg) * ldc + col] = f2b(v[reg]);
            }
        }
    }
}

// ---------------------------------------------------------------- GEMM 64x128
// For the N=1024 GEMMs (attn-out, FF2). Grid = 512 blocks, 48 KiB LDS ->
// 3 blocks/CU. Always: bias + resid + f32 out. Per-wave 32x64, acc[2][4].
__global__ __launch_bounds__(256, 3) void gemm_tall_k(
        const u16* __restrict__ A, const u16* __restrict__ Bt,
        const float* __restrict__ bias, const float* __restrict__ resid,
        float* __restrict__ C, int M, int N, int K, int ldc) {
    __shared__ u16 As[2 * 64 * 64];            // 16 KiB
    __shared__ u16 Bs[2 * 128 * 64];           // 32 KiB
    int tid = threadIdx.x;
    int w = tid >> 6, lane = tid & 63;
    int qd = lane >> 4, l15 = lane & 15;

    // grid = (M/64)*(N/128) = 64*8 = 512. XCD-stripe: 8 m-tiles per XCD.
    int lin = blockIdx.x;
    int xcd = lin & 7, idx = lin >> 3;         // idx 0..63
    int m0 = (xcd * 8 + (idx & 7)) * 64;
    int n0 = (idx >> 3) * 128;

    // Staging: 24 chunks of 1 KiB (8 rows x 64 cols); wave owns 6.
    // chunks 0-7 = A (64 rows), 8-23 = B (128 rows).
    const u16* gsrc[6];
    u16* ldst[6];
    int nboff[6];                              // elem offset to buffer 1
#pragma unroll
    for (int i = 0; i < 6; ++i) {
        int c = w * 6 + i;                     // 0..23
        int isA = c < 8;
        int cb = isA ? c : c - 8;
        int row = cb * 8 + (lane >> 3);
        int cg = (lane & 7) ^ (row & 7);       // XOR swizzle, global side
        gsrc[i] = (isA ? A + (size_t)(m0 + row) * K
                       : Bt + (size_t)(n0 + row) * K) + cg * 8;
        ldst[i] = (isA ? As : Bs) + cb * 512;
        nboff[i] = isA ? 4096 : 8192;
    }

    int wm = w & 1, wn = w >> 1;               // 2x2 waves, 32x64 each
    f32x4 acc[2][4];
#pragma unroll
    for (int mt = 0; mt < 2; ++mt)
#pragma unroll
        for (int nt = 0; nt < 4; ++nt)
            acc[mt][nt] = (f32x4){0.f, 0.f, 0.f, 0.f};

    int aoff[2][2], boff[4][2];
#pragma unroll
    for (int t = 0; t < 2; ++t) {
        int ar = wm * 32 + t * 16 + l15;
#pragma unroll
        for (int h = 0; h < 2; ++h)
            aoff[t][h] = ar * 64 + (((h * 4 + qd) ^ (ar & 7)) * 8);
    }
#pragma unroll
    for (int t = 0; t < 4; ++t) {
        int br = wn * 64 + t * 16 + l15;
#pragma unroll
        for (int h = 0; h < 2; ++h)
            boff[t][h] = br * 64 + (((h * 4 + qd) ^ (br & 7)) * 8);
    }

    // prologue: stage step 0 into buffer 0
#pragma unroll
    for (int i = 0; i < 6; ++i)
        __builtin_amdgcn_global_load_lds(
            (__attribute__((address_space(1))) void*)(gsrc[i]),
            (__attribute__((address_space(3))) void*)(ldst[i]), 16, 0, 0);

    int nsteps = K >> 6;                       // 16 or 48, always even

#define TSTEP64(S, RB)                                                      \
    {                                                                       \
        WAIT_VMCNT0();                                                      \
        __builtin_amdgcn_s_barrier();                                       \
        if ((S) + 1 < nsteps) {                                             \
            int k0 = ((S) + 1) << 6;                                        \
            _Pragma("unroll")                                               \
            for (int i = 0; i < 6; ++i)                                     \
                __builtin_amdgcn_global_load_lds(                           \
                    (__attribute__((address_space(1))) void*)(gsrc[i] + k0),\
                    (__attribute__((address_space(3))) void*)(ldst[i] +     \
                        (1 - (RB)) * nboff[i]),                             \
                    16, 0, 0);                                              \
        }                                                                   \
        bf16x8 av[2][2], bv[4][2];                                          \
        _Pragma("unroll")                                                   \
        for (int t = 0; t < 2; ++t)                                         \
            _Pragma("unroll")                                               \
            for (int h = 0; h < 2; ++h)                                     \
                av[t][h] = *(const bf16x8*)&As[aoff[t][h] + (RB) * 4096];   \
        _Pragma("unroll")                                                   \
        for (int t = 0; t < 4; ++t)                                         \
            _Pragma("unroll")                                               \
            for (int h = 0; h < 2; ++h)                                     \
                bv[t][h] = *(const bf16x8*)&Bs[boff[t][h] + (RB) * 8192];   \
        _Pragma("unroll")                                                   \
        for (int mt = 0; mt < 2; ++mt)                                      \
            _Pragma("unroll")                                               \
            for (int nt = 0; nt < 4; ++nt) {                                \
                acc[mt][nt] = __builtin_amdgcn_mfma_f32_16x16x32_bf16(      \
                    av[mt][0], bv[nt][0], acc[mt][nt], 0, 0, 0);            \
                acc[mt][nt] = __builtin_amdgcn_mfma_f32_16x16x32_bf16(      \
                    av[mt][1], bv[nt][1], acc[mt][nt], 0, 0, 0);            \
            }                                                               \
    }

    for (int s = 0; s < nsteps; s += 2) {
        TSTEP64(s, 0);
        TSTEP64(s + 1, 1);
    }

#pragma unroll
    for (int mt = 0; mt < 2; ++mt) {
        int row0 = m0 + wm * 32 + mt * 16 + qd * 4;
#pragma unroll
        for (int nt = 0; nt < 4; ++nt) {
            int col = n0 + wn * 64 + nt * 16 + l15;
#pragma unroll
            for (int reg = 0; reg < 4; ++reg) {
                float v = acc[mt][nt][reg] + bias[col]
                        + resid[(size_t)(row0 + reg) * ldc + col];
                C[(size_t)(row0 + reg) * ldc + col] = v;
            }
        }
    }
}

// ---------------------------------------------------------------- attention
// Flash-style MFMA; one wave per 16-query tile; <=5 chunks of 32 keys.
// qk buffer layout (bf16): [b, s, {q:0..1023, k:1024..2047}]
__global__ __launch_bounds__(256) void attn_k(
        const u16* __restrict__ qk, const u16* __restrict__ vt,
        u16* __restrict__ ctx) {
    int lane = threadIdx.x & 63, l15 = lane & 15, quad = lane >> 4;
    int t = blockIdx.x * 4 + (threadIdx.x >> 6);
    int qt = t & (SEQ / 16 - 1);
    int h  = (t >> 7) & (NH - 1);
    int b  = t >> 11;
    int q0 = qt * 16;
    int bh = b * NH + h;

    const u16* qrow = qk + (size_t)(b * SEQ + q0 + l15) * (2 * D_MODEL) + h * DH + quad * 8;
    bf16x8 qf0 = *(const bf16x8*)(qrow);
    bf16x8 qf1 = *(const bf16x8*)(qrow + 32);
    const u16* kbase = qk + (size_t)(b * SEQ) * (2 * D_MODEL) + D_MODEL + h * DH + quad * 8;
    const u16* vbase = vt + (size_t)(bh * DH) * SEQ;

    f32x4 o[4] = {{0.f, 0.f, 0.f, 0.f}, {0.f, 0.f, 0.f, 0.f},
                  {0.f, 0.f, 0.f, 0.f}, {0.f, 0.f, 0.f, 0.f}};
    float m = -1e30f, l = 0.f;
    int q = q0 + l15;
    int cs = q0 - (WIN - 1);
    cs = cs < 0 ? 0 : (cs & ~31);

    for (int c = cs; c <= q0 + 15; c += 32) {
        const u16* k0p = kbase + (size_t)(c + l15) * (2 * D_MODEL);
        const u16* k1p = k0p + (size_t)16 * (2 * D_MODEL);
        bf16x8 ka0 = *(const bf16x8*)(k0p);
        bf16x8 ka1 = *(const bf16x8*)(k0p + 32);
        bf16x8 kb0 = *(const bf16x8*)(k1p);
        bf16x8 kb1 = *(const bf16x8*)(k1p + 32);
        f32x4 s0 = {0.f, 0.f, 0.f, 0.f}, s1 = {0.f, 0.f, 0.f, 0.f};
        s0 = __builtin_amdgcn_mfma_f32_16x16x32_bf16(ka0, qf0, s0, 0, 0, 0);
        s0 = __builtin_amdgcn_mfma_f32_16x16x32_bf16(ka1, qf1, s0, 0, 0, 0);
        s1 = __builtin_amdgcn_mfma_f32_16x16x32_bf16(kb0, qf0, s1, 0, 0, 0);
        s1 = __builtin_amdgcn_mfma_f32_16x16x32_bf16(kb1, qf1, s1, 0, 0, 0);

        float p0[4], p1[4];
        float cm = -1e30f;
#pragma unroll
        for (int reg = 0; reg < 4; ++reg) {
            int k0i = c + quad * 4 + reg;
            p0[reg] = ((unsigned)(q - k0i) < WIN) ? s0[reg] * 0.125f : -1e30f;
            p1[reg] = ((unsigned)(q - k0i - 16) < WIN) ? s1[reg] * 0.125f : -1e30f;
            cm = fmaxf(cm, fmaxf(p0[reg], p1[reg]));
        }
        cm = fmaxf(cm, __shfl_xor(cm, 16, 64));
        cm = fmaxf(cm, __shfl_xor(cm, 32, 64));
        float mn = fmaxf(m, cm);
        float alpha = __expf(m - mn);
        m = mn;
        float ls = 0.f;
#pragma unroll
        for (int reg = 0; reg < 4; ++reg) {
            p0[reg] = __expf(p0[reg] - mn);
            p1[reg] = __expf(p1[reg] - mn);
            ls += p0[reg] + p1[reg];
        }
        ls += __shfl_xor(ls, 16, 64);
        ls += __shfl_xor(ls, 32, 64);
        l = l * alpha + ls;
#pragma unroll
        for (int mt = 0; mt < 4; ++mt) o[mt] *= alpha;

        u32 z0 = pk2(p0[0], p0[1]), z1 = pk2(p0[2], p0[3]);
        u32 w0 = pk2(p1[0], p1[1]), w1 = pk2(p1[2], p1[3]);
        int slo = ((quad & 1) * 2) * 16 + l15;
        int shi = slo + 16;
        u32 zl0 = (u32)__shfl((int)z0, slo, 64), zl1 = (u32)__shfl((int)z1, slo, 64);
        u32 zh0 = (u32)__shfl((int)z0, shi, 64), zh1 = (u32)__shfl((int)z1, shi, 64);
        u32 wl0 = (u32)__shfl((int)w0, slo, 64), wl1 = (u32)__shfl((int)w1, slo, 64);
        u32 wh0 = (u32)__shfl((int)w0, shi, 64), wh1 = (u32)__shfl((int)w1, shi, 64);
        alignas(16) u32 pr[4];
        pr[0] = quad < 2 ? zl0 : wl0;
        pr[1] = quad < 2 ? zl1 : wl1;
        pr[2] = quad < 2 ? zh0 : wh0;
        pr[3] = quad < 2 ? zh1 : wh1;
        bf16x8 pf = *(const bf16x8*)pr;

#pragma unroll
        for (int mt = 0; mt < 4; ++mt) {
            bf16x8 vf = *(const bf16x8*)(vbase + (size_t)(mt * 16 + l15) * SEQ + c + quad * 8);
            o[mt] = __builtin_amdgcn_mfma_f32_16x16x32_bf16(vf, pf, o[mt], 0, 0, 0);
        }
    }

    float rdiv = 1.f / l;
    u16* crow = ctx + (size_t)(b * SEQ + q0 + l15) * D_MODEL + h * DH;
#pragma unroll
    for (int mt = 0; mt < 4; ++mt) {
        ushort4 pkv = {f2b(o[mt][0] * rdiv), f2b(o[mt][1] * rdiv),
                       f2b(o[mt][2] * rdiv), f2b(o[mt][3] * rdiv)};
        *(ushort4*)(crow + mt * 16 + quad * 4) = pkv;
    }
}

// ---------------------------------------------------------------- launch
extern "C" void kernel_launch(void* const* d_in, const int* in_sizes, int n_in,
                              void* d_out, int out_size, void* d_ws, size_t ws_size,
                              hipStream_t stream) {
    (void)in_sizes; (void)n_in; (void)out_size; (void)ws_size;
    const float* x     = (const float*)d_in[0];
    const float* w_qkv = (const float*)d_in[1];
    const float* b_qkv = (const float*)d_in[2];
    const float* w_out = (const float*)d_in[3];
    const float* b_out = (const float*)d_in[4];
    const float* w_ff1 = (const float*)d_in[5];
    const float* b_ff1 = (const float*)d_in[6];
    const float* w_ff2 = (const float*)d_in[7];
    const float* b_ff2 = (const float*)d_in[8];
    const float* ln1g  = (const float*)d_in[9];
    const float* ln1b  = (const float*)d_in[10];
    const float* ln2g  = (const float*)d_in[11];
    const float* ln2b  = (const float*)d_in[12];
    float* out = (float*)d_out;

    const int M = BATCH * SEQ;                       // 4096
    char* base = (char*)d_ws;                        // 76 MiB peak
    u16*   hbf   = (u16*)(base);                     //  8 MiB: LN out
    u16*   qkbuf = (u16*)(base + (8ll  << 20));      // 16 MiB: Q,K [b,s,2048]
    u16*   ctxbf = (u16*)(base + (24ll << 20));      //  8 MiB: attn out
    u16*   vtbuf = (u16*)(base + (32ll << 20));      //  8 MiB: V^T [bh][d][s]
    u16*   ffbf  = (u16*)(base + (8ll  << 20));      // 24 MiB: FF inter (overlays qk+ctx, disjoint lifetime)
    float* x2    = (float*)(base + (40ll << 20));    // 16 MiB: f32 residual
    u16*   wqkvT = (u16*)(base + (56ll << 20));      //  6 MiB
    u16*   woutT = (u16*)(base + (62ll << 20));      //  2 MiB
    u16*   wff1T = (u16*)(base + (64ll << 20));      //  6 MiB
    u16*   wff2T = (u16*)(base + (70ll << 20));      //  6 MiB

    // fused: 4 weight transposes (64x64 tiles) + LN1 (all independent)
    prep_k<<<dim3(6656), 256, 0, stream>>>(
        x, ln1g, ln1b, hbf, w_qkv, wqkvT, w_out, woutT,
        w_ff1, wff1T, w_ff2, wff2T);
    // QKV: Q,K -> qkbuf (ldc 2048); V -> vtbuf transposed. 128x64, 1536 blk.
    gemm3_k<0, 1><<<dim3((M / 128) * (3 * D_MODEL / 64)), 256, 0, stream>>>(
        hbf, wqkvT, b_qkv, qkbuf, vtbuf, M, 3 * D_MODEL, D_MODEL, 2 * D_MODEL);
    attn_k<<<dim3(BATCH * NH * (SEQ / 16) / 4), 256, 0, stream>>>(qkbuf, vtbuf, ctxbf);
    // x2 = x + ctx @ w_out + b_out   (64x128 tile, 512 blocks)
    gemm_tall_k<<<dim3(512), 256, 0, stream>>>(
        ctxbf, woutT, b_out, x, x2, M, D_MODEL, D_MODEL, D_MODEL);
    // hbf = bf16(LN2(x2))
    ln_k<<<M, 256, 0, stream>>>(x2, ln2g, ln2b, hbf);
    // ffbf = bf16(gelu(hbf @ w_ff1 + b_ff1))   (128x64, 1536 blocks)
    gemm3_k<1, 0><<<dim3((M / 128) * (DFF / 64)), 256, 0, stream>>>(
        hbf, wff1T, b_ff1, ffbf, nullptr, M, DFF, D_MODEL, DFF);
    // out = x2 + ffbf @ w_ff2 + b_ff2   (64x128 tile, 512 blocks)
    gemm_tall_k<<<dim3(512), 256, 0, stream>>>(
        ffbf, wff2T, b_ff2, x2, out, M, D_MODEL, DFF, D_MODEL);
}